// Round 11
// baseline (100.491 us; speedup 1.0000x reference)
//
#include <hip/hip_runtime.h>
#include <hip/hip_fp16.h>

#define N_NODES  100000
#define N_EDGES  1600000
#define N_GRAPHS 64
#define NBUCK    391                 // ceil(N_NODES / 256)
#define NBLK     256
#define CHUNK    (N_EDGES / NBLK)    // 6250 exactly
#define NODEBLK  1563                // ceil(N_NODES / 64)
#define FCAP     6144                // bucket-size LDS cap (mean 4096, sigma 64)

// ---- workspace layout (int elements). q (fp8, 800K ints) overlays the sort
// scratch, which is dead after k_fine. Max extent 3,802,112 ints = 15.2 MB.
#define OFF_GSTART 0            // 65 -> pad 128
#define OFF_ROWPTR 128          // 100,001 -> pad 100,096
#define OFF_DIS    100224       // 100,000 -> pad 100,096
#define OFF_S      200320       // 200,000 (8B aligned) -> pad 200,064
#define OFF_CSR    400384       // 1,600,000
#define OFF_Q      2000384      // 800,000 ints (100k x 8 dwords of fp8)
#define OFF_BHIST  2000384      // overlays Q (dead after k_scatter; q written later)
#define OFF_BOFFL  2100736      // 100,352
#define OFF_BSUM   2201088      // 391 -> pad 512
#define OFF_BSTART 2201600      // 392 -> pad 512
#define OFF_TMP    2202112      // 1,600,000 (dead after k_fine)

typedef float fvec2 __attribute__((ext_vector_type(2)));

// ---------- scan helpers (block-uniform call sites only; safe for
// back-to-back calls via trailing barrier) ----------
__device__ __forceinline__ int excl_scan_256(int v, int* wsum) {
  int t = threadIdx.x, lane = t & 63, w = t >> 6;
  int x = v;
#pragma unroll
  for (int off = 1; off < 64; off <<= 1) {
    int y = __shfl_up(x, off, 64);
    if (lane >= off) x += y;
  }
  if (lane == 63) wsum[w] = x;
  __syncthreads();
  if (t == 0) {
    int r = 0;
#pragma unroll
    for (int i = 0; i < 4; ++i) { int tv = wsum[i]; wsum[i] = r; r += tv; }
  }
  __syncthreads();
  int res = x - v + wsum[w];
  __syncthreads();
  return res;
}

__device__ __forceinline__ int excl_scan_512(int v, int* wsum) {
  int t = threadIdx.x, lane = t & 63, w = t >> 6;
  int x = v;
#pragma unroll
  for (int off = 1; off < 64; off <<= 1) {
    int y = __shfl_up(x, off, 64);
    if (lane >= off) x += y;
  }
  if (lane == 63) wsum[w] = x;
  __syncthreads();
  if (t == 0) {
    int r = 0;
#pragma unroll
    for (int i = 0; i < 8; ++i) { int tv = wsum[i]; wsum[i] = r; r += tv; }
  }
  __syncthreads();
  int res = x - v + wsum[w];
  __syncthreads();
  return res;
}

// ---------- pass 1: per-block coarse histogram (LDS atomics only) ----------
__global__ void k_hist(const int* __restrict__ dst, int* __restrict__ bhist) {
  __shared__ int hist[NBUCK];
  int t = threadIdx.x, k = blockIdx.x;
  for (int b = t; b < NBUCK; b += 256) hist[b] = 0;
  __syncthreads();
  int e0 = k * CHUNK, e1 = e0 + CHUNK;
  for (int e = e0 + t; e < e1; e += 256) atomicAdd(&hist[dst[e] >> 8], 1);
  __syncthreads();
  for (int b = t; b < NBUCK; b += 256) bhist[b * NBLK + k] = hist[b];
}

// ---------- pass 2a: scan each bucket's per-block counts + graph bounds ----
__global__ void k_scan_a(const int* __restrict__ bhist, int* __restrict__ boffl,
                         int* __restrict__ bsum, const int* __restrict__ batch,
                         int* __restrict__ gstart) {
  __shared__ int wsum[4];
  int t = threadIdx.x, b = blockIdx.x;
  int i = b * 256 + t;
  if (i < N_NODES) {
    int bi = batch[i];
    if (i == 0) {
      for (int g = 0; g <= bi; ++g) gstart[g] = 0;
    } else {
      int bp = batch[i - 1];
      for (int g = bp + 1; g <= bi; ++g) gstart[g] = i;
    }
    if (i == N_NODES - 1) {
      for (int g = bi + 1; g <= N_GRAPHS; ++g) gstart[g] = N_NODES;
    }
  }
  int v = bhist[b * NBLK + t];
  int ex = excl_scan_256(v, wsum);
  boffl[b * NBLK + t] = ex;
  if (t == NBLK - 1) bsum[b] = ex + v;
}

// ---------- pass 2b: scan bucket totals -> bstart; zero pooled output ------
__global__ void k_scan_b(const int* __restrict__ bsum, int* __restrict__ bstart,
                         float* __restrict__ pooled) {
  __shared__ int wsum[8];
  int t = threadIdx.x;
  for (int i = t; i < N_GRAPHS * 32; i += 512) pooled[i] = 0.f;
  int v = (t < NBUCK) ? bsum[t] : 0;
  int ex = excl_scan_512(v, wsum);
  if (t <= NBUCK) bstart[t] = ex;
}

// ---------- pass 3: scatter edges into coarse buckets, LDS-staged ----------
// Edges grouped by bucket in LDS first, then flushed as per-bucket runs with
// 16 lanes / bucket, 4 buckets / wave-instr (coalesced 64B segments).
__global__ void k_scatter(const int* __restrict__ src, const int* __restrict__ dst,
                          const int* __restrict__ bstart, const int* __restrict__ boffl,
                          const int* __restrict__ bhist, int* __restrict__ tmp) {
  __shared__ int ebuf[CHUNK];
  __shared__ int loff[NBUCK];
  __shared__ int fill[NBUCK];
  __shared__ int gbase[NBUCK];
  __shared__ int wsum[4];
  __shared__ int tot0sh;
  int t = threadIdx.x, k = blockIdx.x;
  // block-local bucket offsets: scan this block's bhist column (391 entries)
  int c0 = bhist[t * NBLK + k];
  int ex0 = excl_scan_256(c0, wsum);
  loff[t] = ex0;
  fill[t] = 0;
  gbase[t] = bstart[t] + boffl[t * NBLK + k];
  if (t == 255) tot0sh = ex0 + c0;
  __syncthreads();
  int idx = 256 + t;
  int c1 = (idx < NBUCK) ? bhist[idx * NBLK + k] : 0;
  int ex1 = excl_scan_256(c1, wsum);
  if (idx < NBUCK) {
    loff[idx] = tot0sh + ex1;
    fill[idx] = 0;
    gbase[idx] = bstart[idx] + boffl[idx * NBLK + k];
  }
  __syncthreads();
  // scatter chunk's edges into LDS grouped by bucket
  int e0 = k * CHUNK, e1 = e0 + CHUNK;
  for (int e = e0 + t; e < e1; e += 256) {
    int s_ = src[e], d_ = dst[e];
    int b = d_ >> 8;
    int pos = loff[b] + atomicAdd(&fill[b], 1);
    ebuf[pos] = (s_ << 8) | (d_ & 255);
  }
  __syncthreads();
  // flush: wave wv handles bucket-groups {wv, wv+4, ...}; 4 buckets per group
  int wv = t >> 6;
  int sub = (t >> 4) & 3;
  int off0 = t & 15;
  const int ngroups = (NBUCK + 3) / 4;
  for (int g = wv; g < ngroups; g += 4) {
    int b = g * 4 + sub;
    if (b < NBUCK) {
      int len = fill[b], lb = loff[b], gb = gbase[b];
      for (int o = off0; o < len; o += 16) tmp[gb + o] = ebuf[lb + o];
    }
  }
}

// ---------- pass 4: per-bucket fine CSR + dis + s, fully in LDS ------------
// Loads bucket edges once, permutes in LDS, writes csr_src coalesced.
__global__ void k_fine(const int* __restrict__ tmp, const int* __restrict__ bstart,
                       const float* __restrict__ x, int* __restrict__ csr_src,
                       int* __restrict__ row_ptr, float* __restrict__ dis,
                       float2* __restrict__ s) {
  __shared__ int ebuf[FCAP];
  __shared__ int csrbuf[FCAP];
  __shared__ int hist[256];   // becomes scanned offsets after scan
  __shared__ int fill[256];
  __shared__ int wsum[4];
  int t = threadIdx.x, b = blockIdx.x;
  int base_n = b << 8;
  int e0 = bstart[b], e1 = bstart[b + 1];
  int cnt = e1 - e0;
  bool lds_path = (cnt <= FCAP);
  hist[t] = 0;
  __syncthreads();
  if (lds_path) {
    for (int i = t; i < cnt; i += 256) {
      int p = tmp[e0 + i];
      ebuf[i] = p;
      atomicAdd(&hist[p & 255], 1);
    }
  } else {
    for (int e = e0 + t; e < e1; e += 256) atomicAdd(&hist[tmp[e] & 255], 1);
  }
  __syncthreads();
  int h = hist[t];
  int ex = excl_scan_256(h, wsum);
  hist[t] = ex;
  fill[t] = 0;
  int nn = min(256, N_NODES - base_n);
  if (t < nn) {
    int v = base_n + t;
    row_ptr[v] = e0 + ex;
    float dv = rsqrtf((float)(h + 1));
    dis[v] = dv;
    float2 xv = ((const float2*)x)[v];
    s[v] = make_float2(xv.x * dv, xv.y * dv);
  }
  if (b == NBUCK - 1 && t == 0) row_ptr[N_NODES] = e1;
  __syncthreads();
  if (lds_path) {
    for (int i = t; i < cnt; i += 256) {
      int p = ebuf[i];
      int fine = p & 255;
      int pos = hist[fine] + atomicAdd(&fill[fine], 1);
      csrbuf[pos] = p >> 8;
    }
    __syncthreads();
    for (int i = t; i < cnt; i += 256) csr_src[e0 + i] = csrbuf[i];
  } else {
    for (int e = e0 + t; e < e1; e += 256) {
      int p = tmp[e];
      int fine = p & 255;
      int pos = e0 + hist[fine] + atomicAdd(&fill[fine], 1);
      csr_src[pos] = p >> 8;
    }
  }
}

// ---------- layer 1: 64-thr blocks, TWO nodes per thread (v, v+64).
// Weight LDS broadcasts amortized over both nodes; grid 782 ~ 3.05/CU.
// q = fp8(dis * relu(t@W1+b1) @ W2), 32 B per node. No device fences.
__global__ void __launch_bounds__(64)
k_layer1(const float2* __restrict__ s, const int* __restrict__ row_ptr,
         const int* __restrict__ csr_src, const float* __restrict__ W1,
         const float* __restrict__ b1, const float* __restrict__ W2,
         int4* __restrict__ q8) {
  __shared__ float4 sWB[64];     // {W1[0][j], W1[1][j], b1[j], 0}
  __shared__ float4 sW2[512];    // W2 row-major as float4
  int t = threadIdx.x;
  sWB[t] = make_float4(W1[t], W1[64 + t], b1[t], 0.f);
#pragma unroll
  for (int i = 0; i < 8; ++i) sW2[i * 64 + t] = ((const float4*)W2)[i * 64 + t];
  __syncthreads();
  int base = blockIdx.x * 128;
  int vA = base + t, vB = base + 64 + t;
  bool okA = vA < N_NODES, okB = vB < N_NODES;
  float tA0 = 0.f, tA1 = 0.f, tB0 = 0.f, tB1 = 0.f, dA = 0.f, dB = 0.f;
  if (okA) {
    int beg = row_ptr[vA], end = row_ptr[vA + 1];
    float2 sv = s[vA];
    tA0 = sv.x; tA1 = sv.y;
    int k = beg;
    for (; k + 4 <= end; k += 4) {
      float2 a = s[csr_src[k]], b = s[csr_src[k + 1]];
      float2 c = s[csr_src[k + 2]], d = s[csr_src[k + 3]];
      tA0 += (a.x + b.x) + (c.x + d.x);
      tA1 += (a.y + b.y) + (c.y + d.y);
    }
    for (; k < end; ++k) { float2 su = s[csr_src[k]]; tA0 += su.x; tA1 += su.y; }
    dA = rsqrtf((float)(end - beg + 1));
    tA0 *= dA; tA1 *= dA;
  }
  if (okB) {
    int beg = row_ptr[vB], end = row_ptr[vB + 1];
    float2 sv = s[vB];
    tB0 = sv.x; tB1 = sv.y;
    int k = beg;
    for (; k + 4 <= end; k += 4) {
      float2 a = s[csr_src[k]], b = s[csr_src[k + 1]];
      float2 c = s[csr_src[k + 2]], d = s[csr_src[k + 3]];
      tB0 += (a.x + b.x) + (c.x + d.x);
      tB1 += (a.y + b.y) + (c.y + d.y);
    }
    for (; k < end; ++k) { float2 su = s[csr_src[k]]; tB0 += su.x; tB1 += su.y; }
    dB = rsqrtf((float)(end - beg + 1));
    tB0 *= dB; tB1 *= dB;
  }
  float4 aA[8], aB[8];
#pragma unroll
  for (int m = 0; m < 8; ++m) {
    aA[m] = make_float4(0.f, 0.f, 0.f, 0.f);
    aB[m] = make_float4(0.f, 0.f, 0.f, 0.f);
  }
  for (int j = 0; j < 64; ++j) {
    float4 wb = sWB[j];
    float rA = fmaxf(fmaf(tA0, wb.x, fmaf(tA1, wb.y, wb.z)), 0.f);
    float rB = fmaxf(fmaf(tB0, wb.x, fmaf(tB1, wb.y, wb.z)), 0.f);
#pragma unroll
    for (int m = 0; m < 8; ++m) {
      float4 w = sW2[j * 8 + m];
      aA[m].x = fmaf(rA, w.x, aA[m].x);
      aA[m].y = fmaf(rA, w.y, aA[m].y);
      aA[m].z = fmaf(rA, w.z, aA[m].z);
      aA[m].w = fmaf(rA, w.w, aA[m].w);
      aB[m].x = fmaf(rB, w.x, aB[m].x);
      aB[m].y = fmaf(rB, w.y, aB[m].y);
      aB[m].z = fmaf(rB, w.z, aB[m].z);
      aB[m].w = fmaf(rB, w.w, aB[m].w);
    }
  }
  if (okA) {
    int pk[8];
#pragma unroll
    for (int m = 0; m < 8; ++m) {
      int wrd = __builtin_amdgcn_cvt_pk_fp8_f32(aA[m].x * dA, aA[m].y * dA, 0, false);
      wrd = __builtin_amdgcn_cvt_pk_fp8_f32(aA[m].z * dA, aA[m].w * dA, wrd, true);
      pk[m] = wrd;
    }
    q8[vA * 2]     = make_int4(pk[0], pk[1], pk[2], pk[3]);
    q8[vA * 2 + 1] = make_int4(pk[4], pk[5], pk[6], pk[7]);
  }
  if (okB) {
    int pk[8];
#pragma unroll
    for (int m = 0; m < 8; ++m) {
      int wrd = __builtin_amdgcn_cvt_pk_fp8_f32(aB[m].x * dB, aB[m].y * dB, 0, false);
      wrd = __builtin_amdgcn_cvt_pk_fp8_f32(aB[m].z * dB, aB[m].w * dB, wrd, true);
      pk[m] = wrd;
    }
    q8[vB * 2]     = make_int4(pk[0], pk[1], pk[2], pk[3]);
    q8[vB * 2 + 1] = make_int4(pk[4], pk[5], pk[6], pk[7]);
  }
}

// ---------- layer 2 + pooling (R8-proven geometry, no fences) --------------
__device__ __forceinline__ float4 qdec(unsigned int d) {
  fvec2 lo = __builtin_amdgcn_cvt_pk_f32_fp8(d, false);
  fvec2 hi = __builtin_amdgcn_cvt_pk_f32_fp8(d, true);
  return make_float4(lo.x, lo.y, hi.x, hi.y);
}

__global__ void k_layer2(const unsigned int* __restrict__ q, const float* __restrict__ dis,
                         const int* __restrict__ row_ptr, const int* __restrict__ csr_src,
                         const int* __restrict__ batch, float* __restrict__ pooled) {
  __shared__ float4 red[32][9];    // pad 9 to spread banks
  int t = threadIdx.x;
  int fp = t & 7;           // feature dword 0..7 (4 features each)
  int rg = t >> 3;          // rowgroup 0..31
  int vb = blockIdx.x * 64;
  int nlast = min(vb + 63, N_NODES - 1);
  bool uniform = (batch[vb] == batch[nlast]);
  int v0 = vb + rg * 2;
  int v1 = min(v0 + 2, N_NODES);
  float4 acc = make_float4(0.f, 0.f, 0.f, 0.f);
  int curg = (v0 < N_NODES) ? batch[v0] : -1;
  for (int v = v0; v < v1; ++v) {
    if (!uniform) {
      int g = batch[v];
      if (g != curg) {
        int base = curg * 32 + fp * 4;
        atomicAdd(&pooled[base],     acc.x);
        atomicAdd(&pooled[base + 1], acc.y);
        atomicAdd(&pooled[base + 2], acc.z);
        atomicAdd(&pooled[base + 3], acc.w);
        acc = make_float4(0.f, 0.f, 0.f, 0.f);
        curg = g;
      }
    }
    int e0 = row_ptr[v], e1 = row_ptr[v + 1];
    float4 z = qdec(q[v * 8 + fp]);
    int k = e0;
    for (; k + 8 <= e1; k += 8) {
      int u0 = csr_src[k],     u1 = csr_src[k + 1], u2 = csr_src[k + 2], u3 = csr_src[k + 3];
      int u4 = csr_src[k + 4], u5 = csr_src[k + 5], u6 = csr_src[k + 6], u7 = csr_src[k + 7];
      float4 f0 = qdec(q[u0 * 8 + fp]);
      float4 f1 = qdec(q[u1 * 8 + fp]);
      float4 f2 = qdec(q[u2 * 8 + fp]);
      float4 f3 = qdec(q[u3 * 8 + fp]);
      float4 f4 = qdec(q[u4 * 8 + fp]);
      float4 f5 = qdec(q[u5 * 8 + fp]);
      float4 f6 = qdec(q[u6 * 8 + fp]);
      float4 f7 = qdec(q[u7 * 8 + fp]);
      z.x += ((f0.x + f1.x) + (f2.x + f3.x)) + ((f4.x + f5.x) + (f6.x + f7.x));
      z.y += ((f0.y + f1.y) + (f2.y + f3.y)) + ((f4.y + f5.y) + (f6.y + f7.y));
      z.z += ((f0.z + f1.z) + (f2.z + f3.z)) + ((f4.z + f5.z) + (f6.z + f7.z));
      z.w += ((f0.w + f1.w) + (f2.w + f3.w)) + ((f4.w + f5.w) + (f6.w + f7.w));
    }
    for (; k < e1; ++k) {
      float4 f = qdec(q[csr_src[k] * 8 + fp]);
      z.x += f.x; z.y += f.y; z.z += f.z; z.w += f.w;
    }
    float dvv = dis[v];
    acc.x = fmaf(z.x, dvv, acc.x);
    acc.y = fmaf(z.y, dvv, acc.y);
    acc.z = fmaf(z.z, dvv, acc.z);
    acc.w = fmaf(z.w, dvv, acc.w);
  }
  if (uniform) {
    red[rg][fp] = acc;
    __syncthreads();
    if (t < 8) {
      float4 ssum = make_float4(0.f, 0.f, 0.f, 0.f);
#pragma unroll
      for (int r = 0; r < 32; ++r) {
        float4 x4 = red[r][t];
        ssum.x += x4.x; ssum.y += x4.y; ssum.z += x4.z; ssum.w += x4.w;
      }
      int gg = batch[vb];
      int base = gg * 32 + t * 4;
      atomicAdd(&pooled[base],     ssum.x);
      atomicAdd(&pooled[base + 1], ssum.y);
      atomicAdd(&pooled[base + 2], ssum.z);
      atomicAdd(&pooled[base + 3], ssum.w);
    }
  } else if (v0 < N_NODES) {
    int base = curg * 32 + fp * 4;
    atomicAdd(&pooled[base],     acc.x);
    atomicAdd(&pooled[base + 1], acc.y);
    atomicAdd(&pooled[base + 2], acc.z);
    atomicAdd(&pooled[base + 3], acc.w);
  }
}

// ---------- final: mean + b2 ----------
__global__ void k_final(float* __restrict__ out, const int* __restrict__ gstart,
                        const float* __restrict__ b2) {
  int i = blockIdx.x * 256 + threadIdx.x;
  if (i < N_GRAPHS * 32) {
    int g = i >> 5, l = i & 31;
    int c = gstart[g + 1] - gstart[g];
    out[i] = (c > 0) ? out[i] / (float)c + b2[l] : 0.f;
  }
}

extern "C" void kernel_launch(void* const* d_in, const int* in_sizes, int n_in,
                              void* d_out, int out_size, void* d_ws, size_t ws_size,
                              hipStream_t stream) {
  (void)in_sizes; (void)n_in; (void)out_size; (void)ws_size;
  const float* x   = (const float*)d_in[0];
  const float* W1  = (const float*)d_in[1];
  const float* b1  = (const float*)d_in[2];
  const float* W2  = (const float*)d_in[3];
  const float* b2  = (const float*)d_in[4];
  const int* edge  = (const int*)d_in[5];
  const int* batch = (const int*)d_in[6];
  const int* src = edge;             // edge_index[0]
  const int* dst = edge + N_EDGES;   // edge_index[1]
  float* out = (float*)d_out;

  int* ws      = (int*)d_ws;
  int* gstart  = ws + OFF_GSTART;
  int* row_ptr = ws + OFF_ROWPTR;
  float* dis   = (float*)(ws + OFF_DIS);
  float2* s    = (float2*)(ws + OFF_S);
  int* csr_src = ws + OFF_CSR;
  int4* q8     = (int4*)(ws + OFF_Q);
  int* bhist   = ws + OFF_BHIST;
  int* boffl   = ws + OFF_BOFFL;
  int* bsum    = ws + OFF_BSUM;
  int* bstart  = ws + OFF_BSTART;
  int* tmp     = ws + OFF_TMP;

  k_hist<<<NBLK, 256, 0, stream>>>(dst, bhist);
  k_scan_a<<<NBUCK, 256, 0, stream>>>(bhist, boffl, bsum, batch, gstart);
  k_scan_b<<<1, 512, 0, stream>>>(bsum, bstart, out);
  k_scatter<<<NBLK, 256, 0, stream>>>(src, dst, bstart, boffl, bhist, tmp);
  k_fine<<<NBUCK, 256, 0, stream>>>(tmp, bstart, x, csr_src, row_ptr, dis, s);
  k_layer1<<<(N_NODES + 127) / 128, 64, 0, stream>>>(s, row_ptr, csr_src,
                                                     W1, b1, W2, q8);
  k_layer2<<<NODEBLK, 256, 0, stream>>>((const unsigned int*)q8, dis, row_ptr,
                                        csr_src, batch, out);
  k_final<<<8, 256, 0, stream>>>(out, gstart, b2);
}

// Round 12
// 92.943 us; speedup vs baseline: 1.0812x; 1.0812x over previous
//
#include <hip/hip_runtime.h>
#include <hip/hip_fp16.h>

#define N_NODES  100000
#define N_EDGES  1600000
#define N_GRAPHS 64
#define NBUCK    391                 // ceil(N_NODES / 256)
#define NBLK     256
#define CHUNK    (N_EDGES / NBLK)    // 6250 exactly
#define NODEBLK  1563                // ceil(N_NODES / 64)

// ---- workspace layout (int elements). q (fp8, 800K ints) overlays the sort
// scratch, which is dead after k_fine. Max extent 3,802,112 ints = 15.2 MB.
#define OFF_GSTART 0            // 65 -> pad 128
#define OFF_ROWPTR 128          // 100,001 -> pad 100,096
#define OFF_DIS    100224       // 100,000 -> pad 100,096
#define OFF_S      200320       // 200,000 (8B aligned) -> pad 200,064
#define OFF_CSR    400384       // 1,600,000
#define OFF_Q      2000384      // 800,000 ints (100k x 8 dwords of fp8)
#define OFF_BHIST  2000384      // overlays Q (dead after k_scatter; q written later)
#define OFF_BOFFL  2100736      // 100,352
#define OFF_BSUM   2201088      // 391 -> pad 512
#define OFF_BSTART 2201600      // 392 -> pad 512
#define OFF_TMP    2202112      // 1,600,000 (dead after k_fine)

typedef float fvec2 __attribute__((ext_vector_type(2)));

// ---------- scan helpers (block-uniform call sites only) ----------
__device__ __forceinline__ int excl_scan_256(int v, int* wsum) {
  int t = threadIdx.x, lane = t & 63, w = t >> 6;
  int x = v;
#pragma unroll
  for (int off = 1; off < 64; off <<= 1) {
    int y = __shfl_up(x, off, 64);
    if (lane >= off) x += y;
  }
  if (lane == 63) wsum[w] = x;
  __syncthreads();
  if (t == 0) {
    int r = 0;
#pragma unroll
    for (int i = 0; i < 4; ++i) { int tv = wsum[i]; wsum[i] = r; r += tv; }
  }
  __syncthreads();
  return x - v + wsum[w];
}

__device__ __forceinline__ int excl_scan_512(int v, int* wsum) {
  int t = threadIdx.x, lane = t & 63, w = t >> 6;
  int x = v;
#pragma unroll
  for (int off = 1; off < 64; off <<= 1) {
    int y = __shfl_up(x, off, 64);
    if (lane >= off) x += y;
  }
  if (lane == 63) wsum[w] = x;
  __syncthreads();
  if (t == 0) {
    int r = 0;
#pragma unroll
    for (int i = 0; i < 8; ++i) { int tv = wsum[i]; wsum[i] = r; r += tv; }
  }
  __syncthreads();
  return x - v + wsum[w];
}

// ---------- pass 1: per-block coarse histogram (LDS atomics only) ----------
// dst chunk read as int2 (CHUNK*4 = 25000 B is 8-aligned for every block).
__global__ void k_hist(const int* __restrict__ dst, int* __restrict__ bhist) {
  __shared__ int hist[NBUCK];
  int t = threadIdx.x, k = blockIdx.x;
  for (int b = t; b < NBUCK; b += 256) hist[b] = 0;
  __syncthreads();
  const int2* d2 = (const int2*)(dst + k * CHUNK);
  for (int i = t; i < CHUNK / 2; i += 256) {
    int2 p = d2[i];
    atomicAdd(&hist[p.x >> 8], 1);
    atomicAdd(&hist[p.y >> 8], 1);
  }
  __syncthreads();
  for (int b = t; b < NBUCK; b += 256) bhist[b * NBLK + k] = hist[b];
}

// ---------- pass 2a: scan each bucket's per-block counts + graph bounds ----
__global__ void k_scan_a(const int* __restrict__ bhist, int* __restrict__ boffl,
                         int* __restrict__ bsum, const int* __restrict__ batch,
                         int* __restrict__ gstart) {
  __shared__ int wsum[4];
  int t = threadIdx.x, b = blockIdx.x;
  int i = b * 256 + t;
  if (i < N_NODES) {
    int bi = batch[i];
    if (i == 0) {
      for (int g = 0; g <= bi; ++g) gstart[g] = 0;
    } else {
      int bp = batch[i - 1];
      for (int g = bp + 1; g <= bi; ++g) gstart[g] = i;
    }
    if (i == N_NODES - 1) {
      for (int g = bi + 1; g <= N_GRAPHS; ++g) gstart[g] = N_NODES;
    }
  }
  int v = bhist[b * NBLK + t];
  int ex = excl_scan_256(v, wsum);
  boffl[b * NBLK + t] = ex;
  if (t == NBLK - 1) bsum[b] = ex + v;
}

// ---------- pass 2b: scan bucket totals -> bstart; zero pooled output ------
__global__ void k_scan_b(const int* __restrict__ bsum, int* __restrict__ bstart,
                         float* __restrict__ pooled) {
  __shared__ int wsum[8];
  int t = threadIdx.x;
  for (int i = t; i < N_GRAPHS * 32; i += 512) pooled[i] = 0.f;
  int v = (t < NBUCK) ? bsum[t] : 0;
  int ex = excl_scan_512(v, wsum);
  if (t <= NBUCK) bstart[t] = ex;
}

// ---------- pass 3: scatter edges into coarse buckets (LDS atomics only) ----
// src/dst chunks read as int2 (8-aligned for every block).
__global__ void k_scatter(const int* __restrict__ src, const int* __restrict__ dst,
                          const int* __restrict__ bstart, const int* __restrict__ boffl,
                          int* __restrict__ tmp) {
  __shared__ int sbase[NBUCK];
  __shared__ int fill[NBUCK];
  int t = threadIdx.x, k = blockIdx.x;
  for (int b = t; b < NBUCK; b += 256) {
    sbase[b] = bstart[b] + boffl[b * NBLK + k];
    fill[b] = 0;
  }
  __syncthreads();
  const int2* s2 = (const int2*)(src + k * CHUNK);
  const int2* d2 = (const int2*)(dst + k * CHUNK);
  for (int i = t; i < CHUNK / 2; i += 256) {
    int2 sp = s2[i];
    int2 dp = d2[i];
    int b0 = dp.x >> 8;
    int pos0 = sbase[b0] + atomicAdd(&fill[b0], 1);
    tmp[pos0] = (sp.x << 8) | (dp.x & 255);
    int b1 = dp.y >> 8;
    int pos1 = sbase[b1] + atomicAdd(&fill[b1], 1);
    tmp[pos1] = (sp.y << 8) | (dp.y & 255);
  }
}

// ---------- pass 4: per-bucket fine CSR + dis + s (LDS atomics only) -------
__global__ void k_fine(const int* __restrict__ tmp, const int* __restrict__ bstart,
                       const float* __restrict__ x, int* __restrict__ csr_src,
                       int* __restrict__ row_ptr, float* __restrict__ dis,
                       float2* __restrict__ s) {
  __shared__ int hist[256];   // becomes scanned offsets after scan
  __shared__ int fill[256];
  __shared__ int wsum[4];
  int t = threadIdx.x, b = blockIdx.x;
  int base_n = b << 8;
  int e0 = bstart[b], e1 = bstart[b + 1];
  hist[t] = 0;
  __syncthreads();
  for (int e = e0 + t; e < e1; e += 256) atomicAdd(&hist[tmp[e] & 255], 1);
  __syncthreads();
  int h = hist[t];
  int ex = excl_scan_256(h, wsum);
  hist[t] = ex;
  fill[t] = 0;
  int nn = min(256, N_NODES - base_n);
  if (t < nn) {
    int v = base_n + t;
    row_ptr[v] = e0 + ex;
    float dv = rsqrtf((float)(h + 1));
    dis[v] = dv;
    float2 xv = ((const float2*)x)[v];
    s[v] = make_float2(xv.x * dv, xv.y * dv);
  }
  if (b == NBUCK - 1 && t == 0) row_ptr[N_NODES] = e1;
  __syncthreads();
  for (int e = e0 + t; e < e1; e += 256) {
    int p = tmp[e];
    int fine = p & 255;
    int pos = e0 + hist[fine] + atomicAdd(&fill[fine], 1);
    csr_src[pos] = p >> 8;
  }
}

// ---------- layer 1: 64-thr blocks, TWO nodes per thread (v, v+64).
// Weight LDS broadcasts amortized over both nodes; grid 782 ~ 3.05/CU.
// q = fp8(dis * relu(t@W1+b1) @ W2), 32 B per node. No device fences.
__global__ void __launch_bounds__(64)
k_layer1(const float2* __restrict__ s, const int* __restrict__ row_ptr,
         const int* __restrict__ csr_src, const float* __restrict__ W1,
         const float* __restrict__ b1, const float* __restrict__ W2,
         int4* __restrict__ q8) {
  __shared__ float4 sWB[64];     // {W1[0][j], W1[1][j], b1[j], 0}
  __shared__ float4 sW2[512];    // W2 row-major as float4
  int t = threadIdx.x;
  sWB[t] = make_float4(W1[t], W1[64 + t], b1[t], 0.f);
#pragma unroll
  for (int i = 0; i < 8; ++i) sW2[i * 64 + t] = ((const float4*)W2)[i * 64 + t];
  __syncthreads();
  int base = blockIdx.x * 128;
  int vA = base + t, vB = base + 64 + t;
  bool okA = vA < N_NODES, okB = vB < N_NODES;
  float tA0 = 0.f, tA1 = 0.f, tB0 = 0.f, tB1 = 0.f, dA = 0.f, dB = 0.f;
  if (okA) {
    int beg = row_ptr[vA], end = row_ptr[vA + 1];
    float2 sv = s[vA];
    tA0 = sv.x; tA1 = sv.y;
    int k = beg;
    for (; k + 4 <= end; k += 4) {
      float2 a = s[csr_src[k]], b = s[csr_src[k + 1]];
      float2 c = s[csr_src[k + 2]], d = s[csr_src[k + 3]];
      tA0 += (a.x + b.x) + (c.x + d.x);
      tA1 += (a.y + b.y) + (c.y + d.y);
    }
    for (; k < end; ++k) { float2 su = s[csr_src[k]]; tA0 += su.x; tA1 += su.y; }
    dA = rsqrtf((float)(end - beg + 1));
    tA0 *= dA; tA1 *= dA;
  }
  if (okB) {
    int beg = row_ptr[vB], end = row_ptr[vB + 1];
    float2 sv = s[vB];
    tB0 = sv.x; tB1 = sv.y;
    int k = beg;
    for (; k + 4 <= end; k += 4) {
      float2 a = s[csr_src[k]], b = s[csr_src[k + 1]];
      float2 c = s[csr_src[k + 2]], d = s[csr_src[k + 3]];
      tB0 += (a.x + b.x) + (c.x + d.x);
      tB1 += (a.y + b.y) + (c.y + d.y);
    }
    for (; k < end; ++k) { float2 su = s[csr_src[k]]; tB0 += su.x; tB1 += su.y; }
    dB = rsqrtf((float)(end - beg + 1));
    tB0 *= dB; tB1 *= dB;
  }
  float4 aA[8], aB[8];
#pragma unroll
  for (int m = 0; m < 8; ++m) {
    aA[m] = make_float4(0.f, 0.f, 0.f, 0.f);
    aB[m] = make_float4(0.f, 0.f, 0.f, 0.f);
  }
  for (int j = 0; j < 64; ++j) {
    float4 wb = sWB[j];
    float rA = fmaxf(fmaf(tA0, wb.x, fmaf(tA1, wb.y, wb.z)), 0.f);
    float rB = fmaxf(fmaf(tB0, wb.x, fmaf(tB1, wb.y, wb.z)), 0.f);
#pragma unroll
    for (int m = 0; m < 8; ++m) {
      float4 w = sW2[j * 8 + m];
      aA[m].x = fmaf(rA, w.x, aA[m].x);
      aA[m].y = fmaf(rA, w.y, aA[m].y);
      aA[m].z = fmaf(rA, w.z, aA[m].z);
      aA[m].w = fmaf(rA, w.w, aA[m].w);
      aB[m].x = fmaf(rB, w.x, aB[m].x);
      aB[m].y = fmaf(rB, w.y, aB[m].y);
      aB[m].z = fmaf(rB, w.z, aB[m].z);
      aB[m].w = fmaf(rB, w.w, aB[m].w);
    }
  }
  if (okA) {
    int pk[8];
#pragma unroll
    for (int m = 0; m < 8; ++m) {
      int wrd = __builtin_amdgcn_cvt_pk_fp8_f32(aA[m].x * dA, aA[m].y * dA, 0, false);
      wrd = __builtin_amdgcn_cvt_pk_fp8_f32(aA[m].z * dA, aA[m].w * dA, wrd, true);
      pk[m] = wrd;
    }
    q8[vA * 2]     = make_int4(pk[0], pk[1], pk[2], pk[3]);
    q8[vA * 2 + 1] = make_int4(pk[4], pk[5], pk[6], pk[7]);
  }
  if (okB) {
    int pk[8];
#pragma unroll
    for (int m = 0; m < 8; ++m) {
      int wrd = __builtin_amdgcn_cvt_pk_fp8_f32(aB[m].x * dB, aB[m].y * dB, 0, false);
      wrd = __builtin_amdgcn_cvt_pk_fp8_f32(aB[m].z * dB, aB[m].w * dB, wrd, true);
      pk[m] = wrd;
    }
    q8[vB * 2]     = make_int4(pk[0], pk[1], pk[2], pk[3]);
    q8[vB * 2 + 1] = make_int4(pk[4], pk[5], pk[6], pk[7]);
  }
}

// ---------- layer 2 + pooling (R8-proven geometry, no fences) --------------
__device__ __forceinline__ float4 qdec(unsigned int d) {
  fvec2 lo = __builtin_amdgcn_cvt_pk_f32_fp8(d, false);
  fvec2 hi = __builtin_amdgcn_cvt_pk_f32_fp8(d, true);
  return make_float4(lo.x, lo.y, hi.x, hi.y);
}

__global__ void k_layer2(const unsigned int* __restrict__ q, const float* __restrict__ dis,
                         const int* __restrict__ row_ptr, const int* __restrict__ csr_src,
                         const int* __restrict__ batch, float* __restrict__ pooled) {
  __shared__ float4 red[32][9];    // pad 9 to spread banks
  int t = threadIdx.x;
  int fp = t & 7;           // feature dword 0..7 (4 features each)
  int rg = t >> 3;          // rowgroup 0..31
  int vb = blockIdx.x * 64;
  int nlast = min(vb + 63, N_NODES - 1);
  bool uniform = (batch[vb] == batch[nlast]);
  int v0 = vb + rg * 2;
  int v1 = min(v0 + 2, N_NODES);
  float4 acc = make_float4(0.f, 0.f, 0.f, 0.f);
  int curg = (v0 < N_NODES) ? batch[v0] : -1;
  for (int v = v0; v < v1; ++v) {
    if (!uniform) {
      int g = batch[v];
      if (g != curg) {
        int base = curg * 32 + fp * 4;
        atomicAdd(&pooled[base],     acc.x);
        atomicAdd(&pooled[base + 1], acc.y);
        atomicAdd(&pooled[base + 2], acc.z);
        atomicAdd(&pooled[base + 3], acc.w);
        acc = make_float4(0.f, 0.f, 0.f, 0.f);
        curg = g;
      }
    }
    int e0 = row_ptr[v], e1 = row_ptr[v + 1];
    float4 z = qdec(q[v * 8 + fp]);
    int k = e0;
    for (; k + 8 <= e1; k += 8) {
      int u0 = csr_src[k],     u1 = csr_src[k + 1], u2 = csr_src[k + 2], u3 = csr_src[k + 3];
      int u4 = csr_src[k + 4], u5 = csr_src[k + 5], u6 = csr_src[k + 6], u7 = csr_src[k + 7];
      float4 f0 = qdec(q[u0 * 8 + fp]);
      float4 f1 = qdec(q[u1 * 8 + fp]);
      float4 f2 = qdec(q[u2 * 8 + fp]);
      float4 f3 = qdec(q[u3 * 8 + fp]);
      float4 f4 = qdec(q[u4 * 8 + fp]);
      float4 f5 = qdec(q[u5 * 8 + fp]);
      float4 f6 = qdec(q[u6 * 8 + fp]);
      float4 f7 = qdec(q[u7 * 8 + fp]);
      z.x += ((f0.x + f1.x) + (f2.x + f3.x)) + ((f4.x + f5.x) + (f6.x + f7.x));
      z.y += ((f0.y + f1.y) + (f2.y + f3.y)) + ((f4.y + f5.y) + (f6.y + f7.y));
      z.z += ((f0.z + f1.z) + (f2.z + f3.z)) + ((f4.z + f5.z) + (f6.z + f7.z));
      z.w += ((f0.w + f1.w) + (f2.w + f3.w)) + ((f4.w + f5.w) + (f6.w + f7.w));
    }
    for (; k < e1; ++k) {
      float4 f = qdec(q[csr_src[k] * 8 + fp]);
      z.x += f.x; z.y += f.y; z.z += f.z; z.w += f.w;
    }
    float dvv = dis[v];
    acc.x = fmaf(z.x, dvv, acc.x);
    acc.y = fmaf(z.y, dvv, acc.y);
    acc.z = fmaf(z.z, dvv, acc.z);
    acc.w = fmaf(z.w, dvv, acc.w);
  }
  if (uniform) {
    red[rg][fp] = acc;
    __syncthreads();
    if (t < 8) {
      float4 ssum = make_float4(0.f, 0.f, 0.f, 0.f);
#pragma unroll
      for (int r = 0; r < 32; ++r) {
        float4 x4 = red[r][t];
        ssum.x += x4.x; ssum.y += x4.y; ssum.z += x4.z; ssum.w += x4.w;
      }
      int gg = batch[vb];
      int base = gg * 32 + t * 4;
      atomicAdd(&pooled[base],     ssum.x);
      atomicAdd(&pooled[base + 1], ssum.y);
      atomicAdd(&pooled[base + 2], ssum.z);
      atomicAdd(&pooled[base + 3], ssum.w);
    }
  } else if (v0 < N_NODES) {
    int base = curg * 32 + fp * 4;
    atomicAdd(&pooled[base],     acc.x);
    atomicAdd(&pooled[base + 1], acc.y);
    atomicAdd(&pooled[base + 2], acc.z);
    atomicAdd(&pooled[base + 3], acc.w);
  }
}

// ---------- final: mean + b2 ----------
__global__ void k_final(float* __restrict__ out, const int* __restrict__ gstart,
                        const float* __restrict__ b2) {
  int i = blockIdx.x * 256 + threadIdx.x;
  if (i < N_GRAPHS * 32) {
    int g = i >> 5, l = i & 31;
    int c = gstart[g + 1] - gstart[g];
    out[i] = (c > 0) ? out[i] / (float)c + b2[l] : 0.f;
  }
}

extern "C" void kernel_launch(void* const* d_in, const int* in_sizes, int n_in,
                              void* d_out, int out_size, void* d_ws, size_t ws_size,
                              hipStream_t stream) {
  (void)in_sizes; (void)n_in; (void)out_size; (void)ws_size;
  const float* x   = (const float*)d_in[0];
  const float* W1  = (const float*)d_in[1];
  const float* b1  = (const float*)d_in[2];
  const float* W2  = (const float*)d_in[3];
  const float* b2  = (const float*)d_in[4];
  const int* edge  = (const int*)d_in[5];
  const int* batch = (const int*)d_in[6];
  const int* src = edge;             // edge_index[0]
  const int* dst = edge + N_EDGES;   // edge_index[1]
  float* out = (float*)d_out;

  int* ws      = (int*)d_ws;
  int* gstart  = ws + OFF_GSTART;
  int* row_ptr = ws + OFF_ROWPTR;
  float* dis   = (float*)(ws + OFF_DIS);
  float2* s    = (float2*)(ws + OFF_S);
  int* csr_src = ws + OFF_CSR;
  int4* q8     = (int4*)(ws + OFF_Q);
  int* bhist   = ws + OFF_BHIST;
  int* boffl   = ws + OFF_BOFFL;
  int* bsum    = ws + OFF_BSUM;
  int* bstart  = ws + OFF_BSTART;
  int* tmp     = ws + OFF_TMP;

  k_hist<<<NBLK, 256, 0, stream>>>(dst, bhist);
  k_scan_a<<<NBUCK, 256, 0, stream>>>(bhist, boffl, bsum, batch, gstart);
  k_scan_b<<<1, 512, 0, stream>>>(bsum, bstart, out);
  k_scatter<<<NBLK, 256, 0, stream>>>(src, dst, bstart, boffl, tmp);
  k_fine<<<NBUCK, 256, 0, stream>>>(tmp, bstart, x, csr_src, row_ptr, dis, s);
  k_layer1<<<(N_NODES + 127) / 128, 64, 0, stream>>>(s, row_ptr, csr_src,
                                                     W1, b1, W2, q8);
  k_layer2<<<NODEBLK, 256, 0, stream>>>((const unsigned int*)q8, dis, row_ptr,
                                        csr_src, batch, out);
  k_final<<<8, 256, 0, stream>>>(out, gstart, b2);
}

// Round 13
// 91.137 us; speedup vs baseline: 1.1026x; 1.0198x over previous
//
#include <hip/hip_runtime.h>
#include <hip/hip_fp16.h>

#define N_NODES  100000
#define N_EDGES  1600000
#define N_GRAPHS 64
#define NBUCK    391                 // ceil(N_NODES / 256)
#define NBLK     256
#define CHUNK    (N_EDGES / NBLK)    // 6250 exactly
#define NODEBLK  1563                // ceil(N_NODES / 64)

// ---- workspace layout (int elements). q (fp8, 800K ints) overlays the sort
// scratch, which is dead after k_fine. Max extent 3,802,112 ints = 15.2 MB.
#define OFF_GSTART 0            // 65 -> pad 128
#define OFF_ROWPTR 128          // 100,001 -> pad 100,096
#define OFF_DIS    100224       // 100,000 -> pad 100,096
#define OFF_S      200320       // 200,000 (8B aligned) -> pad 200,064
#define OFF_CSR    400384       // 1,600,000
#define OFF_Q      2000384      // 800,000 ints (100k x 8 dwords of fp8)
#define OFF_BHIST  2000384      // overlays Q (dead after k_scatter; q written later)
#define OFF_BOFFL  2100736      // 100,352
#define OFF_BSUM   2201088      // 391 -> pad 512
#define OFF_BSTART 2201600      // 392 -> pad 512
#define OFF_TMP    2202112      // 1,600,000 (dead after k_fine)

typedef float fvec2 __attribute__((ext_vector_type(2)));

// ---------- scan helper (block-uniform call sites; caller must barrier
// between back-to-back calls — all call sites below do) ----------
__device__ __forceinline__ int excl_scan_256(int v, int* wsum) {
  int t = threadIdx.x, lane = t & 63, w = t >> 6;
  int x = v;
#pragma unroll
  for (int off = 1; off < 64; off <<= 1) {
    int y = __shfl_up(x, off, 64);
    if (lane >= off) x += y;
  }
  if (lane == 63) wsum[w] = x;
  __syncthreads();
  if (t == 0) {
    int r = 0;
#pragma unroll
    for (int i = 0; i < 4; ++i) { int tv = wsum[i]; wsum[i] = r; r += tv; }
  }
  __syncthreads();
  return x - v + wsum[w];
}

// ---------- pass 1: per-block coarse histogram; block 0 zeroes pooled ------
// dst chunk read as int2 (CHUNK*4 = 25000 B is 8-aligned for every block).
__global__ void k_hist(const int* __restrict__ dst, int* __restrict__ bhist,
                       float* __restrict__ pooled) {
  __shared__ int hist[NBUCK];
  int t = threadIdx.x, k = blockIdx.x;
  if (k == 0) {
    for (int i = t; i < N_GRAPHS * 32; i += 256) pooled[i] = 0.f;
  }
  for (int b = t; b < NBUCK; b += 256) hist[b] = 0;
  __syncthreads();
  const int2* d2 = (const int2*)(dst + k * CHUNK);
  for (int i = t; i < CHUNK / 2; i += 256) {
    int2 p = d2[i];
    atomicAdd(&hist[p.x >> 8], 1);
    atomicAdd(&hist[p.y >> 8], 1);
  }
  __syncthreads();
  for (int b = t; b < NBUCK; b += 256) bhist[b * NBLK + k] = hist[b];
}

// ---------- pass 2: scan each bucket's per-block counts + graph bounds -----
__global__ void k_scan_a(const int* __restrict__ bhist, int* __restrict__ boffl,
                         int* __restrict__ bsum, const int* __restrict__ batch,
                         int* __restrict__ gstart) {
  __shared__ int wsum[4];
  int t = threadIdx.x, b = blockIdx.x;
  int i = b * 256 + t;
  if (i < N_NODES) {
    int bi = batch[i];
    if (i == 0) {
      for (int g = 0; g <= bi; ++g) gstart[g] = 0;
    } else {
      int bp = batch[i - 1];
      for (int g = bp + 1; g <= bi; ++g) gstart[g] = i;
    }
    if (i == N_NODES - 1) {
      for (int g = bi + 1; g <= N_GRAPHS; ++g) gstart[g] = N_NODES;
    }
  }
  int v = bhist[b * NBLK + t];
  int ex = excl_scan_256(v, wsum);
  boffl[b * NBLK + t] = ex;
  if (t == NBLK - 1) bsum[b] = ex + v;
}

// ---------- pass 3: scatter edges into coarse buckets (LDS atomics only) ----
// Each block recomputes bstart from bsum (two-round LDS scan) — replaces the
// old k_scan_b dispatch. Block 0 persists bstart to global for k_fine.
// src/dst chunks read as int2 (8-aligned for every block).
__global__ void k_scatter(const int* __restrict__ src, const int* __restrict__ dst,
                          const int* __restrict__ bsum, const int* __restrict__ boffl,
                          int* __restrict__ bstart, int* __restrict__ tmp) {
  __shared__ int sbase[NBUCK];
  __shared__ int fill[NBUCK];
  __shared__ int wsum[4];
  __shared__ int tot0sh;
  int t = threadIdx.x, k = blockIdx.x;
  // round 1: scan bsum[0..255]
  int v0 = bsum[t];
  int ex0 = excl_scan_256(v0, wsum);
  sbase[t] = ex0;
  if (t == 255) tot0sh = ex0 + v0;
  __syncthreads();
  // round 2: scan bsum[256..390] with offset
  int idx = 256 + t;
  int v1 = (idx < NBUCK) ? bsum[idx] : 0;
  int ex1 = excl_scan_256(v1, wsum);
  if (idx < NBUCK) sbase[idx] = tot0sh + ex1;
  __syncthreads();
  if (k == 0) {
    for (int b = t; b < NBUCK; b += 256) bstart[b] = sbase[b];
    if (t == 0) bstart[NBUCK] = N_EDGES;
  }
  // add this block's intra-bucket offset (same thread->b mapping as above)
  for (int b = t; b < NBUCK; b += 256) {
    sbase[b] += boffl[b * NBLK + k];
    fill[b] = 0;
  }
  __syncthreads();
  const int2* s2 = (const int2*)(src + k * CHUNK);
  const int2* d2 = (const int2*)(dst + k * CHUNK);
  for (int i = t; i < CHUNK / 2; i += 256) {
    int2 sp = s2[i];
    int2 dp = d2[i];
    int b0 = dp.x >> 8;
    int pos0 = sbase[b0] + atomicAdd(&fill[b0], 1);
    tmp[pos0] = (sp.x << 8) | (dp.x & 255);
    int b1 = dp.y >> 8;
    int pos1 = sbase[b1] + atomicAdd(&fill[b1], 1);
    tmp[pos1] = (sp.y << 8) | (dp.y & 255);
  }
}

// ---------- pass 4: per-bucket fine CSR + dis + s (LDS atomics only) -------
// tmp reads int2-vectorized with alignment peel + per-half bounds checks.
__global__ void k_fine(const int* __restrict__ tmp, const int* __restrict__ bstart,
                       const float* __restrict__ x, int* __restrict__ csr_src,
                       int* __restrict__ row_ptr, float* __restrict__ dis,
                       float2* __restrict__ s) {
  __shared__ int hist[256];   // becomes scanned offsets after scan
  __shared__ int fill[256];
  __shared__ int wsum[4];
  int t = threadIdx.x, b = blockIdx.x;
  int base_n = b << 8;
  int e0 = bstart[b], e1 = bstart[b + 1];
  int ebase = e0 & ~1;
  int n2 = (e1 - ebase + 1) >> 1;
  const int2* t2 = (const int2*)(tmp + ebase);
  hist[t] = 0;
  __syncthreads();
  for (int i = t; i < n2; i += 256) {
    int2 p = t2[i];
    int i0 = ebase + 2 * i;
    if (i0 >= e0) atomicAdd(&hist[p.x & 255], 1);
    if (i0 + 1 < e1) atomicAdd(&hist[p.y & 255], 1);
  }
  __syncthreads();
  int h = hist[t];
  int ex = excl_scan_256(h, wsum);
  hist[t] = ex;
  fill[t] = 0;
  int nn = min(256, N_NODES - base_n);
  if (t < nn) {
    int v = base_n + t;
    row_ptr[v] = e0 + ex;
    float dv = rsqrtf((float)(h + 1));
    dis[v] = dv;
    float2 xv = ((const float2*)x)[v];
    s[v] = make_float2(xv.x * dv, xv.y * dv);
  }
  if (b == NBUCK - 1 && t == 0) row_ptr[N_NODES] = e1;
  __syncthreads();
  for (int i = t; i < n2; i += 256) {
    int2 p = t2[i];
    int i0 = ebase + 2 * i;
    if (i0 >= e0) {
      int fine = p.x & 255;
      int pos = e0 + hist[fine] + atomicAdd(&fill[fine], 1);
      csr_src[pos] = p.x >> 8;
    }
    if (i0 + 1 < e1) {
      int fine = p.y & 255;
      int pos = e0 + hist[fine] + atomicAdd(&fill[fine], 1);
      csr_src[pos] = p.y >> 8;
    }
  }
}

// ---------- layer 1: 64-thr blocks, TWO nodes per thread (v, v+64).
// Weight LDS broadcasts amortized over both nodes; grid 782 ~ 3.05/CU.
// q = fp8(dis * relu(t@W1+b1) @ W2), 32 B per node. No device fences.
__global__ void __launch_bounds__(64)
k_layer1(const float2* __restrict__ s, const int* __restrict__ row_ptr,
         const int* __restrict__ csr_src, const float* __restrict__ W1,
         const float* __restrict__ b1, const float* __restrict__ W2,
         int4* __restrict__ q8) {
  __shared__ float4 sWB[64];     // {W1[0][j], W1[1][j], b1[j], 0}
  __shared__ float4 sW2[512];    // W2 row-major as float4
  int t = threadIdx.x;
  sWB[t] = make_float4(W1[t], W1[64 + t], b1[t], 0.f);
#pragma unroll
  for (int i = 0; i < 8; ++i) sW2[i * 64 + t] = ((const float4*)W2)[i * 64 + t];
  __syncthreads();
  int base = blockIdx.x * 128;
  int vA = base + t, vB = base + 64 + t;
  bool okA = vA < N_NODES, okB = vB < N_NODES;
  float tA0 = 0.f, tA1 = 0.f, tB0 = 0.f, tB1 = 0.f, dA = 0.f, dB = 0.f;
  if (okA) {
    int beg = row_ptr[vA], end = row_ptr[vA + 1];
    float2 sv = s[vA];
    tA0 = sv.x; tA1 = sv.y;
    int k = beg;
    for (; k + 4 <= end; k += 4) {
      float2 a = s[csr_src[k]], b = s[csr_src[k + 1]];
      float2 c = s[csr_src[k + 2]], d = s[csr_src[k + 3]];
      tA0 += (a.x + b.x) + (c.x + d.x);
      tA1 += (a.y + b.y) + (c.y + d.y);
    }
    for (; k < end; ++k) { float2 su = s[csr_src[k]]; tA0 += su.x; tA1 += su.y; }
    dA = rsqrtf((float)(end - beg + 1));
    tA0 *= dA; tA1 *= dA;
  }
  if (okB) {
    int beg = row_ptr[vB], end = row_ptr[vB + 1];
    float2 sv = s[vB];
    tB0 = sv.x; tB1 = sv.y;
    int k = beg;
    for (; k + 4 <= end; k += 4) {
      float2 a = s[csr_src[k]], b = s[csr_src[k + 1]];
      float2 c = s[csr_src[k + 2]], d = s[csr_src[k + 3]];
      tB0 += (a.x + b.x) + (c.x + d.x);
      tB1 += (a.y + b.y) + (c.y + d.y);
    }
    for (; k < end; ++k) { float2 su = s[csr_src[k]]; tB0 += su.x; tB1 += su.y; }
    dB = rsqrtf((float)(end - beg + 1));
    tB0 *= dB; tB1 *= dB;
  }
  float4 aA[8], aB[8];
#pragma unroll
  for (int m = 0; m < 8; ++m) {
    aA[m] = make_float4(0.f, 0.f, 0.f, 0.f);
    aB[m] = make_float4(0.f, 0.f, 0.f, 0.f);
  }
  for (int j = 0; j < 64; ++j) {
    float4 wb = sWB[j];
    float rA = fmaxf(fmaf(tA0, wb.x, fmaf(tA1, wb.y, wb.z)), 0.f);
    float rB = fmaxf(fmaf(tB0, wb.x, fmaf(tB1, wb.y, wb.z)), 0.f);
#pragma unroll
    for (int m = 0; m < 8; ++m) {
      float4 w = sW2[j * 8 + m];
      aA[m].x = fmaf(rA, w.x, aA[m].x);
      aA[m].y = fmaf(rA, w.y, aA[m].y);
      aA[m].z = fmaf(rA, w.z, aA[m].z);
      aA[m].w = fmaf(rA, w.w, aA[m].w);
      aB[m].x = fmaf(rB, w.x, aB[m].x);
      aB[m].y = fmaf(rB, w.y, aB[m].y);
      aB[m].z = fmaf(rB, w.z, aB[m].z);
      aB[m].w = fmaf(rB, w.w, aB[m].w);
    }
  }
  if (okA) {
    int pk[8];
#pragma unroll
    for (int m = 0; m < 8; ++m) {
      int wrd = __builtin_amdgcn_cvt_pk_fp8_f32(aA[m].x * dA, aA[m].y * dA, 0, false);
      wrd = __builtin_amdgcn_cvt_pk_fp8_f32(aA[m].z * dA, aA[m].w * dA, wrd, true);
      pk[m] = wrd;
    }
    q8[vA * 2]     = make_int4(pk[0], pk[1], pk[2], pk[3]);
    q8[vA * 2 + 1] = make_int4(pk[4], pk[5], pk[6], pk[7]);
  }
  if (okB) {
    int pk[8];
#pragma unroll
    for (int m = 0; m < 8; ++m) {
      int wrd = __builtin_amdgcn_cvt_pk_fp8_f32(aB[m].x * dB, aB[m].y * dB, 0, false);
      wrd = __builtin_amdgcn_cvt_pk_fp8_f32(aB[m].z * dB, aB[m].w * dB, wrd, true);
      pk[m] = wrd;
    }
    q8[vB * 2]     = make_int4(pk[0], pk[1], pk[2], pk[3]);
    q8[vB * 2 + 1] = make_int4(pk[4], pk[5], pk[6], pk[7]);
  }
}

// ---------- layer 2 + pooling (R8-proven geometry, no fences) --------------
__device__ __forceinline__ float4 qdec(unsigned int d) {
  fvec2 lo = __builtin_amdgcn_cvt_pk_f32_fp8(d, false);
  fvec2 hi = __builtin_amdgcn_cvt_pk_f32_fp8(d, true);
  return make_float4(lo.x, lo.y, hi.x, hi.y);
}

__global__ void k_layer2(const unsigned int* __restrict__ q, const float* __restrict__ dis,
                         const int* __restrict__ row_ptr, const int* __restrict__ csr_src,
                         const int* __restrict__ batch, float* __restrict__ pooled) {
  __shared__ float4 red[32][9];    // pad 9 to spread banks
  int t = threadIdx.x;
  int fp = t & 7;           // feature dword 0..7 (4 features each)
  int rg = t >> 3;          // rowgroup 0..31
  int vb = blockIdx.x * 64;
  int nlast = min(vb + 63, N_NODES - 1);
  bool uniform = (batch[vb] == batch[nlast]);
  int v0 = vb + rg * 2;
  int v1 = min(v0 + 2, N_NODES);
  float4 acc = make_float4(0.f, 0.f, 0.f, 0.f);
  int curg = (v0 < N_NODES) ? batch[v0] : -1;
  for (int v = v0; v < v1; ++v) {
    if (!uniform) {
      int g = batch[v];
      if (g != curg) {
        int base = curg * 32 + fp * 4;
        atomicAdd(&pooled[base],     acc.x);
        atomicAdd(&pooled[base + 1], acc.y);
        atomicAdd(&pooled[base + 2], acc.z);
        atomicAdd(&pooled[base + 3], acc.w);
        acc = make_float4(0.f, 0.f, 0.f, 0.f);
        curg = g;
      }
    }
    int e0 = row_ptr[v], e1 = row_ptr[v + 1];
    float4 z = qdec(q[v * 8 + fp]);
    int k = e0;
    for (; k + 8 <= e1; k += 8) {
      int u0 = csr_src[k],     u1 = csr_src[k + 1], u2 = csr_src[k + 2], u3 = csr_src[k + 3];
      int u4 = csr_src[k + 4], u5 = csr_src[k + 5], u6 = csr_src[k + 6], u7 = csr_src[k + 7];
      float4 f0 = qdec(q[u0 * 8 + fp]);
      float4 f1 = qdec(q[u1 * 8 + fp]);
      float4 f2 = qdec(q[u2 * 8 + fp]);
      float4 f3 = qdec(q[u3 * 8 + fp]);
      float4 f4 = qdec(q[u4 * 8 + fp]);
      float4 f5 = qdec(q[u5 * 8 + fp]);
      float4 f6 = qdec(q[u6 * 8 + fp]);
      float4 f7 = qdec(q[u7 * 8 + fp]);
      z.x += ((f0.x + f1.x) + (f2.x + f3.x)) + ((f4.x + f5.x) + (f6.x + f7.x));
      z.y += ((f0.y + f1.y) + (f2.y + f3.y)) + ((f4.y + f5.y) + (f6.y + f7.y));
      z.z += ((f0.z + f1.z) + (f2.z + f3.z)) + ((f4.z + f5.z) + (f6.z + f7.z));
      z.w += ((f0.w + f1.w) + (f2.w + f3.w)) + ((f4.w + f5.w) + (f6.w + f7.w));
    }
    for (; k < e1; ++k) {
      float4 f = qdec(q[csr_src[k] * 8 + fp]);
      z.x += f.x; z.y += f.y; z.z += f.z; z.w += f.w;
    }
    float dvv = dis[v];
    acc.x = fmaf(z.x, dvv, acc.x);
    acc.y = fmaf(z.y, dvv, acc.y);
    acc.z = fmaf(z.z, dvv, acc.z);
    acc.w = fmaf(z.w, dvv, acc.w);
  }
  if (uniform) {
    red[rg][fp] = acc;
    __syncthreads();
    if (t < 8) {
      float4 ssum = make_float4(0.f, 0.f, 0.f, 0.f);
#pragma unroll
      for (int r = 0; r < 32; ++r) {
        float4 x4 = red[r][t];
        ssum.x += x4.x; ssum.y += x4.y; ssum.z += x4.z; ssum.w += x4.w;
      }
      int gg = batch[vb];
      int base = gg * 32 + t * 4;
      atomicAdd(&pooled[base],     ssum.x);
      atomicAdd(&pooled[base + 1], ssum.y);
      atomicAdd(&pooled[base + 2], ssum.z);
      atomicAdd(&pooled[base + 3], ssum.w);
    }
  } else if (v0 < N_NODES) {
    int base = curg * 32 + fp * 4;
    atomicAdd(&pooled[base],     acc.x);
    atomicAdd(&pooled[base + 1], acc.y);
    atomicAdd(&pooled[base + 2], acc.z);
    atomicAdd(&pooled[base + 3], acc.w);
  }
}

// ---------- final: mean + b2 ----------
__global__ void k_final(float* __restrict__ out, const int* __restrict__ gstart,
                        const float* __restrict__ b2) {
  int i = blockIdx.x * 256 + threadIdx.x;
  if (i < N_GRAPHS * 32) {
    int g = i >> 5, l = i & 31;
    int c = gstart[g + 1] - gstart[g];
    out[i] = (c > 0) ? out[i] / (float)c + b2[l] : 0.f;
  }
}

extern "C" void kernel_launch(void* const* d_in, const int* in_sizes, int n_in,
                              void* d_out, int out_size, void* d_ws, size_t ws_size,
                              hipStream_t stream) {
  (void)in_sizes; (void)n_in; (void)out_size; (void)ws_size;
  const float* x   = (const float*)d_in[0];
  const float* W1  = (const float*)d_in[1];
  const float* b1  = (const float*)d_in[2];
  const float* W2  = (const float*)d_in[3];
  const float* b2  = (const float*)d_in[4];
  const int* edge  = (const int*)d_in[5];
  const int* batch = (const int*)d_in[6];
  const int* src = edge;             // edge_index[0]
  const int* dst = edge + N_EDGES;   // edge_index[1]
  float* out = (float*)d_out;

  int* ws      = (int*)d_ws;
  int* gstart  = ws + OFF_GSTART;
  int* row_ptr = ws + OFF_ROWPTR;
  float* dis   = (float*)(ws + OFF_DIS);
  float2* s    = (float2*)(ws + OFF_S);
  int* csr_src = ws + OFF_CSR;
  int4* q8     = (int4*)(ws + OFF_Q);
  int* bhist   = ws + OFF_BHIST;
  int* boffl   = ws + OFF_BOFFL;
  int* bsum    = ws + OFF_BSUM;
  int* bstart  = ws + OFF_BSTART;
  int* tmp     = ws + OFF_TMP;

  k_hist<<<NBLK, 256, 0, stream>>>(dst, bhist, out);
  k_scan_a<<<NBUCK, 256, 0, stream>>>(bhist, boffl, bsum, batch, gstart);
  k_scatter<<<NBLK, 256, 0, stream>>>(src, dst, bsum, boffl, bstart, tmp);
  k_fine<<<NBUCK, 256, 0, stream>>>(tmp, bstart, x, csr_src, row_ptr, dis, s);
  k_layer1<<<(N_NODES + 127) / 128, 64, 0, stream>>>(s, row_ptr, csr_src,
                                                     W1, b1, W2, q8);
  k_layer2<<<NODEBLK, 256, 0, stream>>>((const unsigned int*)q8, dis, row_ptr,
                                        csr_src, batch, out);
  k_final<<<8, 256, 0, stream>>>(out, gstart, b2);
}